// Round 3
// baseline (471.743 us; speedup 1.0000x reference)
//
#include <hip/hip_runtime.h>
#include <hip/hip_cooperative_groups.h>
#include <math.h>

// GAE backward scan, single cooperative kernel.
//   adv[t] = delta[t] + g*adv[t+1], delta[t] = r[t] + 0.99*v[t+1] - v[t], g=0.9405
//
// R5 redesign: DRAM-efficiency, not latency, was the limiter (R1 occupancy 2x
// -> +9.5%; R2 real pipeline -> +4%; Little's law says 10KB/CU in flight
// suffices and we had >32KB). Old layout: block = 64 float2 columns x 16
// t-chunk waves -> every access a 512B island, 128KB stride -> DRAM
// activate-bound at ~3 TB/s (48%).
// New decomposition: block = (column-group, t-chunk). 16 cg x 1024 float2
// columns x 16 tc x 64 rows = 256 blocks (1/CU), 16 waves all scanning the
// SAME t-rows over ADJACENT columns -> 8KB contiguous per row-step (16x longer
// bursts). Chunk aggregate == stored partial at row t_lo (no workspace).
// Cross-block combine via cooperative grid sync:
//   phase1 partial scan -> grid.sync -> snapshot 15 agg rows to regs (K-fold)
//   -> grid.sync (fixup writes must not race agg reads) -> fixup own chunk:
//   out[t] += g^(t_hi+1-t) * K.  Chunk 15 carry is 0, skips fixup.
// Phase-1/3 software pipeline (4-buffer round-robin, sched_barrier) kept from R2.

#define T_OUT 1023
#define B2    16384          // 32768 floats / 2 per lane
#define NW    16             // waves per block (all same t-chunk, adjacent cols)
#define NT_C  16             // t-chunks
#define S_CH  64             // chunk length (last chunk: 63)

#define GAMMA_F 0.99f
#define GL_F    0.9405f      // (float)(0.99*0.95)
#define INVG_F  1.0632642212653909f   // 1/0.9405

typedef float f2v __attribute__((ext_vector_type(2)));

static __device__ __forceinline__ void nt_store_f2(float2* dst, float2 v) {
  __builtin_nontemporal_store(*(const f2v*)&v, (f2v*)dst);
}

#define STEP2(r, v)                                  \
  p.x = (r).x + GAMMA_F * vn.x - (v).x + GL_F * p.x; \
  p.y = (r).y + GAMMA_F * vn.y - (v).y + GL_F * p.y;

// ---- phase-1 pipeline pieces (backward in t) ----
#define P1_LOADQ(rB_, vB_, tt)                       \
  _Pragma("unroll")                                  \
  for (int k = 0; k < 4; ++k) {                      \
    rB_[k] = rp[((tt) - k) * B2];                    \
    vB_[k] = vp[((tt) - k) * B2];                    \
  }

#define P1_COMPQ(rB_, vB_, tt)                       \
  _Pragma("unroll")                                  \
  for (int k = 0; k < 4; ++k) {                      \
    STEP2(rB_[k], vB_[k])                            \
    op[((tt) - k) * B2] = p;                         \
    vn = vB_[k];                                     \
  }

// prefetch quads (tp, tp-4) into P/Q, compute quads (tc_, tc_-4) from X/Y
#define P1_BODY(rP, vP, rQ, vQ, rX, vX, rY, vY)      \
  P1_LOADQ(rP, vP, tp)                               \
  P1_LOADQ(rQ, vQ, tp - 4)                           \
  __builtin_amdgcn_sched_barrier(0);                 \
  P1_COMPQ(rX, vX, tcur)                             \
  P1_COMPQ(rY, vY, tcur - 4)                         \
  tcur -= 8; tp -= 8;

#define P1_EPI(rX, vX, rY, vY)                       \
  P1_COMPQ(rX, vX, tcur)                             \
  P1_COMPQ(rY, vY, tcur - 4)

// ---- phase-3 pipeline pieces (forward in t, += x with x *= 1/g per row) ----
#define P3_LOADQ(oB_, uu)                            \
  _Pragma("unroll")                                  \
  for (int k = 0; k < 4; ++k) oB_[k] = op[((uu) + k) * B2];

#define P3_COMPQ(oB_, uu)                            \
  _Pragma("unroll")                                  \
  for (int k = 0; k < 4; ++k) {                      \
    oB_[k].x += x.x; oB_[k].y += x.y;                \
    nt_store_f2(&op[((uu) + k) * B2], oB_[k]);       \
    x.x *= INVG_F; x.y *= INVG_F;                    \
  }

#define P3_BODY(oP, oQ, oX, oY)                      \
  P3_LOADQ(oP, up)                                   \
  P3_LOADQ(oQ, up + 4)                               \
  __builtin_amdgcn_sched_barrier(0);                 \
  P3_COMPQ(oX, uc)                                   \
  P3_COMPQ(oY, uc + 4)                               \
  uc += 8; up += 8;

#define P3_EPI(oX, oY)                               \
  P3_COMPQ(oX, uc)                                   \
  P3_COMPQ(oY, uc + 4)

__global__ __launch_bounds__(1024, 4) void gae_fused(
    const float2* __restrict__ r2, const float2* __restrict__ v2,
    float2* __restrict__ o2, float gS_full, float gS_last) {
  const int lane = threadIdx.x & 63;
  const int w    = threadIdx.x >> 6;              // wave id = column sub-group
  const int cg   = blockIdx.x & 15;               // column group (1024 float2)
  const int tcnk = blockIdx.x >> 4;               // t-chunk id

  const int q    = cg * 1024 + w * 64 + lane;     // float2 column index
  const int t_lo = tcnk * S_CH;
  const int t_hi = (tcnk == NT_C - 1) ? (T_OUT - 1) : (t_lo + S_CH - 1);

  const float2* rp = r2 + q;
  const float2* vp = v2 + q;
  float2*       op = o2 + q;

  // ---------------- phase 1: zero-carry partial scan (backward) ----------------
  float2 vn = vp[(t_hi + 1) * B2];
  float2 p  = make_float2(0.f, 0.f);

  int t = t_hi;
  if (tcnk == NT_C - 1) {
    // last chunk has len 63; peel 7 rows (one batched round trip) so the
    // remaining 56 rows = 14 quads (even -> fits the 2-quad body pipeline).
    float2 rr[7], vv[7];
#pragma unroll
    for (int k = 0; k < 7; ++k) { rr[k] = rp[(t - k) * B2]; vv[k] = vp[(t - k) * B2]; }
#pragma unroll
    for (int k = 0; k < 7; ++k) {
      STEP2(rr[k], vv[k])
      op[(t - k) * B2] = p;
      vn = vv[k];
    }
    t -= 7;
  }

  {
    float2 rA[4], vA[4], rB[4], vB[4], rC[4], vC[4], rD[4], vD[4];
    int tcur = t;          // top t of next quad pair to compute
    int tp   = t - 8;      // top t of next quad pair to prefetch

    // preload first two quads
    P1_LOADQ(rA, vA, tcur)
    P1_LOADQ(rB, vB, tcur - 4)

    // nb bodies, each computes 2 quads + prefetches 2 quads.
    // len 64 -> nb = 7 (epilogue on C,D); len 56 -> nb = 6 (epilogue on A,B).
    const int nb = ((t - t_lo + 1) >> 3) - 1;
    int i = 0;
    for (; i + 2 <= nb; i += 2) {
      P1_BODY(rC, vC, rD, vD, rA, vA, rB, vB)
      P1_BODY(rA, vA, rB, vB, rC, vC, rD, vD)
    }
    if (i < nb) {
      P1_BODY(rC, vC, rD, vD, rA, vA, rB, vB)
      P1_EPI(rC, vC, rD, vD)
    } else {
      P1_EPI(rA, vA, rB, vB)
    }
  }
  // out[t_lo] now holds this chunk's aggregate (zero-carry partial at t_lo).

  // ------------- phase 2: cross-block combine via grid sync -------------
  cooperative_groups::this_grid().sync();

  // Snapshot later chunks' aggregate rows (out[64j], j > tcnk) BEFORE anyone
  // fixes them up, fold into carry K. Wave-coherent 512B reads, L2/L3-hot.
  float2 K = make_float2(0.f, 0.f);
  for (int j = NT_C - 1; j > tcnk; --j) {         // block-uniform trip count
    const float gj = (j == NT_C - 1) ? gS_last : gS_full;
    float2 a = op[(j * S_CH) * B2];
    K.x = a.x + gj * K.x;
    K.y = a.y + gj * K.y;
  }

  cooperative_groups::this_grid().sync();         // fixup writes must not race agg reads

  // ---------------- phase 3: fix-up own chunk (forward, cache-hot) ------------
  if (tcnk < NT_C - 1) {                          // last chunk: K == 0, skip
    // x(t) = g^(t_hi+1-t) * K; at t_lo that is g^64 * K, then *= 1/g going up.
    float2 x = make_float2(gS_full * K.x, gS_full * K.y);
    float2 oA[4], oB[4], oC[4], oD[4];
    int uc = t_lo;         // next quad pair to compute (forward)
    int up = t_lo + 8;     // next quad pair to prefetch

    P3_LOADQ(oA, uc)
    P3_LOADQ(oB, uc + 4)

    // len 64 -> 16 quads -> 7 bodies: (CD,AB) x3 + CD, epilogue on C,D.
#pragma unroll 1
    for (int i = 0; i < 3; ++i) {
      P3_BODY(oC, oD, oA, oB)
      P3_BODY(oA, oB, oC, oD)
    }
    P3_BODY(oC, oD, oA, oB)
    P3_EPI(oC, oD)
  }
}

extern "C" void kernel_launch(void* const* d_in, const int* in_sizes, int n_in,
                              void* d_out, int out_size, void* d_ws, size_t ws_size,
                              hipStream_t stream) {
  const float2* r2 = (const float2*)d_in[0];
  const float2* v2 = (const float2*)d_in[1];
  float2* o2 = (float2*)d_out;

  const double g = (double)GL_F;
  float gS_full = (float)pow(g, S_CH);       // chunks 0..14 (len 64)
  float gS_last = (float)pow(g, S_CH - 1);   // chunk 15 (63 rows)

  // 16 column-groups x 16 t-chunks = 256 blocks (1/CU), 1024 threads.
  // Cooperative launch: all 256 blocks co-resident (1024 thr, VGPR<=128 via
  // launch_bounds), grid.sync() used for the cross-chunk combine.
  void* args[] = {(void*)&r2, (void*)&v2, (void*)&o2, (void*)&gS_full, (void*)&gS_last};
  hipLaunchCooperativeKernel((const void*)gae_fused, dim3(NT_C * 16), dim3(1024),
                             args, 0, stream);
}

// Round 4
// 404.797 us; speedup vs baseline: 1.1654x; 1.1654x over previous
//
#include <hip/hip_runtime.h>
#include <math.h>

// GAE backward scan, float4-lane cooperative kernel.
//   adv[t] = delta[t] + g*adv[t+1], delta[t] = r[t] + 0.99*v[t+1] - v[t], g=0.9405
//
// R6: R3 falsified nothing -- its "8KB bursts" were 16 drifting waves of 512B
// islands plus 2 grid syncs. This round tests access GRANULARITY cleanly:
// 16 B/lane float4 (the 6.3 TB/s copy ubench shape: 1KB per wave-access).
// Decomposition: 128 column strips (64 lanes x 4 floats = 256 floats) x 32
// t-chunks of 32 rows. Block = 16 waves = 16 chunks = one t-HALF of one strip.
// 256 blocks (1/CU): blockIdx 0..127 = upper half (rows 512..1023, autonomous),
// 128..255 = lower half (rows 0..511, needs upper's aggregate).
// Intra-block combine via LDS (R2 pattern). Cross-block: upper block's wave 0
// publishes C_15 (1KB aggregate row) to d_ws + release-flag; lower block
// acquire-spins (upper never waits; pair shares an XCD since 128%8==0).
// Flags memset each launch (graph-replay safe). Cooperative launch ONLY for
// guaranteed co-residency -- no grid.sync.
// Fixup: out[t] += g^(t_hi+1-t) * K, K folded from LDS aggs (+ partner agg for
// lower half). Global chunk 31 (rows 992..1022, len 31) has K=0, skips fixup.

#define T_OUT 1023
#define B4    8192           // 32768 floats / 4 = float4 per row
#define NW    16             // waves per block (= chunks per half)

#define GAMMA_F 0.99f
#define GL_F    0.9405f      // (float)(0.99*0.95)
#define INVG_F  1.0632642212653909f   // 1/0.9405

typedef float f4v __attribute__((ext_vector_type(4)));

static __device__ __forceinline__ void nt_store_f4(float4* dst, float4 v) {
  __builtin_nontemporal_store(*(const f4v*)&v, (f4v*)dst);
}

#define STEP4(r, v)                                  \
  p.x = (r).x + GAMMA_F * vn.x - (v).x + GL_F * p.x; \
  p.y = (r).y + GAMMA_F * vn.y - (v).y + GL_F * p.y; \
  p.z = (r).z + GAMMA_F * vn.z - (v).z + GL_F * p.z; \
  p.w = (r).w + GAMMA_F * vn.w - (v).w + GL_F * p.w;

// ---- phase-1 pipeline (backward in t, batches of 4 rows) ----
#define P1_LOADQ(rB_, vB_, tt)                       \
  _Pragma("unroll")                                  \
  for (int k = 0; k < 4; ++k) {                      \
    rB_[k] = rp[((tt) - k) * B4];                    \
    vB_[k] = vp[((tt) - k) * B4];                    \
  }

#define P1_COMPQ(rB_, vB_, tt)                       \
  _Pragma("unroll")                                  \
  for (int k = 0; k < 4; ++k) {                      \
    STEP4(rB_[k], vB_[k])                            \
    op[((tt) - k) * B4] = p;                         \
    vn = vB_[k];                                     \
  }

#define P1_BODY(rP, vP, rX, vX)                      \
  P1_LOADQ(rP, vP, tp)                               \
  __builtin_amdgcn_sched_barrier(0);                 \
  P1_COMPQ(rX, vX, tcur)                             \
  tcur -= 4; tp -= 4;

#define P1_EPI(rX, vX) P1_COMPQ(rX, vX, tcur)

// ---- phase-3 pipeline (forward in t, += x with x *= 1/g per row) ----
#define P3_LOADQ(oB_, uu)                            \
  _Pragma("unroll")                                  \
  for (int k = 0; k < 4; ++k) oB_[k] = op[((uu) + k) * B4];

#define P3_COMPQ(oB_, uu)                            \
  _Pragma("unroll")                                  \
  for (int k = 0; k < 4; ++k) {                      \
    oB_[k].x += x.x; oB_[k].y += x.y;                \
    oB_[k].z += x.z; oB_[k].w += x.w;                \
    nt_store_f4(&op[((uu) + k) * B4], oB_[k]);       \
    x.x *= INVG_F; x.y *= INVG_F;                    \
    x.z *= INVG_F; x.w *= INVG_F;                    \
  }

#define P3_BODY(oP, oX)                              \
  P3_LOADQ(oP, up2)                                  \
  __builtin_amdgcn_sched_barrier(0);                 \
  P3_COMPQ(oX, uc)                                   \
  uc += 4; up2 += 4;

#define P3_EPI(oX) P3_COMPQ(oX, uc)

__global__ __launch_bounds__(1024, 4) void gae_fused(
    const float4* __restrict__ r4, const float4* __restrict__ v4,
    float4* __restrict__ o4, float* __restrict__ agg_ws,
    unsigned* __restrict__ flag_ws, float gS32) {
  __shared__ float4 aggs[NW][64];

  const int lane  = threadIdx.x & 63;
  const int wl    = threadIdx.x >> 6;             // local wave/chunk id
  const int upper = (blockIdx.x < 128);           // upper t-half dispatched first
  const int s     = upper ? blockIdx.x : (blockIdx.x - 128);  // strip id
  const int q4    = s * 64 + lane;                // float4 column index

  const int t_lo   = ((upper ? NW : 0) + wl) * 32;
  const int is_top = (upper && wl == NW - 1);     // global chunk 31
  const int t_hi   = is_top ? (T_OUT - 1) : (t_lo + 31);

  const float4* rp = r4 + q4;
  const float4* vp = v4 + q4;
  float4*       op = o4 + q4;

  // ---------------- phase 1: zero-carry partial scan (backward) ----------------
  float4 vn = vp[(t_hi + 1) * B4];
  float4 p  = make_float4(0.f, 0.f, 0.f, 0.f);

  int t = t_hi;
  if (is_top) {
    // len 31: peel 3 rows (one batched round trip) -> 28 left (7 batches).
    float4 rr[3], vv[3];
#pragma unroll
    for (int k = 0; k < 3; ++k) { rr[k] = rp[(t - k) * B4]; vv[k] = vp[(t - k) * B4]; }
#pragma unroll
    for (int k = 0; k < 3; ++k) {
      STEP4(rr[k], vv[k])
      op[(t - k) * B4] = p;
      vn = vv[k];
    }
    t -= 3;
  }

  {
    float4 rA[4], vA[4], rB[4], vB[4];
    int tcur = t;          // top t of next batch to compute
    int tp   = t - 4;      // top t of next batch to prefetch

    P1_LOADQ(rA, vA, tcur)
    const int nb = ((t - t_lo + 1) >> 2) - 1;     // 7 (len 32) or 6 (len 28)
    int i = 0;
    for (; i + 2 <= nb; i += 2) {
      P1_BODY(rB, vB, rA, vA)
      P1_BODY(rA, vA, rB, vB)
    }
    if (i < nb) {
      P1_BODY(rB, vB, rA, vA)
      P1_EPI(rB, vB)
    } else {
      P1_EPI(rA, vA)
    }
  }
  // p == this chunk's aggregate A (zero-carry partial at t_lo).

  // ---------------- phase 2: combine (LDS local + partner handshake) ----------
  aggs[wl][lane] = p;
  __syncthreads();

  float4 K;
  if (upper) {
    K = make_float4(0.f, 0.f, 0.f, 0.f);
  } else {
    // wait for partner (upper half of same strip) to publish C_15
    while (__hip_atomic_load(&flag_ws[s * 16], __ATOMIC_ACQUIRE,
                             __HIP_MEMORY_SCOPE_AGENT) == 0u)
      __builtin_amdgcn_s_sleep(2);
    float* src = agg_ws + s * 256 + lane * 4;
    K.x = __hip_atomic_load(src + 0, __ATOMIC_RELAXED, __HIP_MEMORY_SCOPE_AGENT);
    K.y = __hip_atomic_load(src + 1, __ATOMIC_RELAXED, __HIP_MEMORY_SCOPE_AGENT);
    K.z = __hip_atomic_load(src + 2, __ATOMIC_RELAXED, __HIP_MEMORY_SCOPE_AGENT);
    K.w = __hip_atomic_load(src + 3, __ATOMIC_RELAXED, __HIP_MEMORY_SCOPE_AGENT);
  }
  // K = carry into local chunk 15's top; fold local later chunks down to wl+1.
  for (int j = NW - 1; j > wl; --j) {             // wave-uniform trip count
    float4 a = aggs[j][lane];
    K.x = a.x + gS32 * K.x;
    K.y = a.y + gS32 * K.y;
    K.z = a.z + gS32 * K.z;
    K.w = a.w + gS32 * K.w;
  }
  // K == C_chunk (true carry into own chunk). For global chunk 31, K == 0.

  if (upper && wl == 0) {
    // publish C_15 = A_16 + g^32 * C_16  (p = A_16, K = C_16 here)
    float* dst = agg_ws + s * 256 + lane * 4;
    __hip_atomic_store(dst + 0, p.x + gS32 * K.x, __ATOMIC_RELAXED, __HIP_MEMORY_SCOPE_AGENT);
    __hip_atomic_store(dst + 1, p.y + gS32 * K.y, __ATOMIC_RELAXED, __HIP_MEMORY_SCOPE_AGENT);
    __hip_atomic_store(dst + 2, p.z + gS32 * K.z, __ATOMIC_RELAXED, __HIP_MEMORY_SCOPE_AGENT);
    __hip_atomic_store(dst + 3, p.w + gS32 * K.w, __ATOMIC_RELAXED, __HIP_MEMORY_SCOPE_AGENT);
    __threadfence();
    if (lane == 0)
      __hip_atomic_store(&flag_ws[s * 16], 1u, __ATOMIC_RELEASE, __HIP_MEMORY_SCOPE_AGENT);
  }

  // ---------------- phase 3: fix-up own chunk (forward, cache-hot) ------------
  if (!is_top) {
    // x(t) = g^(t_hi+1-t) * K; at t_lo that is g^32 * K, then *= 1/g going up.
    float4 x = make_float4(gS32 * K.x, gS32 * K.y, gS32 * K.z, gS32 * K.w);
    float4 oA[4], oB[4];
    int uc  = t_lo;        // next batch to compute (forward)
    int up2 = t_lo + 4;    // next batch to prefetch

    P3_LOADQ(oA, uc)
    // 8 batches -> 7 bodies: 3x(B,A / A,B) + (B,A), epilogue on B.
    P3_BODY(oB, oA)
    P3_BODY(oA, oB)
    P3_BODY(oB, oA)
    P3_BODY(oA, oB)
    P3_BODY(oB, oA)
    P3_BODY(oA, oB)
    P3_BODY(oB, oA)
    P3_EPI(oB)
  }
}

extern "C" void kernel_launch(void* const* d_in, const int* in_sizes, int n_in,
                              void* d_out, int out_size, void* d_ws, size_t ws_size,
                              hipStream_t stream) {
  const float4* r4 = (const float4*)d_in[0];
  const float4* v4 = (const float4*)d_in[1];
  float4* o4 = (float4*)d_out;

  // workspace: 128 strips x 256 floats aggregates (128 KB), then 128 flags
  // at 64 B stride (8 KB).
  float*    agg_ws  = (float*)d_ws;
  unsigned* flag_ws = (unsigned*)((char*)d_ws + 128 * 1024);
  float gS32 = (float)pow((double)GL_F, 32);

  // reset flags every launch (stream-ordered, graph-capturable)
  hipMemsetAsync((void*)flag_ws, 0, 128 * 64, stream);

  // 256 blocks (128 upper halves first, then 128 lower) x 1024 threads.
  // Cooperative launch for guaranteed co-residency (spin-wait safety);
  // no grid.sync anywhere.
  void* args[] = {(void*)&r4, (void*)&v4, (void*)&o4,
                  (void*)&agg_ws, (void*)&flag_ws, (void*)&gS32};
  hipLaunchCooperativeKernel((const void*)gae_fused, dim3(256), dim3(1024),
                             args, 0, stream);
}

// Round 5
// 384.972 us; speedup vs baseline: 1.2254x; 1.0515x over previous
//
#include <hip/hip_runtime.h>
#include <math.h>

// GAE backward scan, float4-lane kernel, NORMAL launch.
//   adv[t] = delta[t] + g*adv[t+1], delta[t] = r[t] + 0.99*v[t+1] - v[t], g=0.9405
//
// R5 = R4 byte-identical kernel with ONE variable flipped: plain <<<>>> launch
// instead of hipLaunchCooperativeKernel. R3 (coop, 2.2 TB/s) and R4 (coop,
// 2.4 TB/s) both regressed vs R2 (normal, 3.0 TB/s) despite disjoint
// structures -> coop launch is the prime suspect. This is the clean A/B.
// Handshake is deadlock-safe under FIFO dispatch without co-residency:
// producers (blocks 0..127, upper t-half) dispatch before consumers
// (128..255), producers never wait (rocPRIM decoupled-lookback reasoning).
//
// Decomposition: 128 column strips (64 lanes x float4 = 1KB row slice) x 32
// t-chunks of 32 rows. Block = 16 waves = 16 chunks = one t-HALF of a strip.
// blockIdx 0..127: rows 512..1022 (autonomous). 128..255: rows 0..511.
// Intra-block combine via LDS; cross-block via d_ws agg row + release flag.
// Fixup: out[t] += g^(t_hi+1-t) * K. Global chunk 31 has K=0, skips fixup.

#define T_OUT 1023
#define B4    8192           // 32768 floats / 4 = float4 per row
#define NW    16             // waves per block (= chunks per half)

#define GAMMA_F 0.99f
#define GL_F    0.9405f      // (float)(0.99*0.95)
#define INVG_F  1.0632642212653909f   // 1/0.9405

typedef float f4v __attribute__((ext_vector_type(4)));

static __device__ __forceinline__ void nt_store_f4(float4* dst, float4 v) {
  __builtin_nontemporal_store(*(const f4v*)&v, (f4v*)dst);
}

#define STEP4(r, v)                                  \
  p.x = (r).x + GAMMA_F * vn.x - (v).x + GL_F * p.x; \
  p.y = (r).y + GAMMA_F * vn.y - (v).y + GL_F * p.y; \
  p.z = (r).z + GAMMA_F * vn.z - (v).z + GL_F * p.z; \
  p.w = (r).w + GAMMA_F * vn.w - (v).w + GL_F * p.w;

// ---- phase-1 pipeline (backward in t, batches of 4 rows) ----
#define P1_LOADQ(rB_, vB_, tt)                       \
  _Pragma("unroll")                                  \
  for (int k = 0; k < 4; ++k) {                      \
    rB_[k] = rp[((tt) - k) * B4];                    \
    vB_[k] = vp[((tt) - k) * B4];                    \
  }

#define P1_COMPQ(rB_, vB_, tt)                       \
  _Pragma("unroll")                                  \
  for (int k = 0; k < 4; ++k) {                      \
    STEP4(rB_[k], vB_[k])                            \
    op[((tt) - k) * B4] = p;                         \
    vn = vB_[k];                                     \
  }

#define P1_BODY(rP, vP, rX, vX)                      \
  P1_LOADQ(rP, vP, tp)                               \
  __builtin_amdgcn_sched_barrier(0);                 \
  P1_COMPQ(rX, vX, tcur)                             \
  tcur -= 4; tp -= 4;

#define P1_EPI(rX, vX) P1_COMPQ(rX, vX, tcur)

// ---- phase-3 pipeline (forward in t, += x with x *= 1/g per row) ----
#define P3_LOADQ(oB_, uu)                            \
  _Pragma("unroll")                                  \
  for (int k = 0; k < 4; ++k) oB_[k] = op[((uu) + k) * B4];

#define P3_COMPQ(oB_, uu)                            \
  _Pragma("unroll")                                  \
  for (int k = 0; k < 4; ++k) {                      \
    oB_[k].x += x.x; oB_[k].y += x.y;                \
    oB_[k].z += x.z; oB_[k].w += x.w;                \
    nt_store_f4(&op[((uu) + k) * B4], oB_[k]);       \
    x.x *= INVG_F; x.y *= INVG_F;                    \
    x.z *= INVG_F; x.w *= INVG_F;                    \
  }

#define P3_BODY(oP, oX)                              \
  P3_LOADQ(oP, up2)                                  \
  __builtin_amdgcn_sched_barrier(0);                 \
  P3_COMPQ(oX, uc)                                   \
  uc += 4; up2 += 4;

#define P3_EPI(oX) P3_COMPQ(oX, uc)

__global__ __launch_bounds__(1024, 4) void gae_fused(
    const float4* __restrict__ r4, const float4* __restrict__ v4,
    float4* __restrict__ o4, float* __restrict__ agg_ws,
    unsigned* __restrict__ flag_ws, float gS32) {
  __shared__ float4 aggs[NW][64];

  const int lane  = threadIdx.x & 63;
  const int wl    = threadIdx.x >> 6;             // local wave/chunk id
  const int upper = (blockIdx.x < 128);           // upper t-half dispatched first
  const int s     = upper ? blockIdx.x : (blockIdx.x - 128);  // strip id
  const int q4    = s * 64 + lane;                // float4 column index

  const int t_lo   = ((upper ? NW : 0) + wl) * 32;
  const int is_top = (upper && wl == NW - 1);     // global chunk 31
  const int t_hi   = is_top ? (T_OUT - 1) : (t_lo + 31);

  const float4* rp = r4 + q4;
  const float4* vp = v4 + q4;
  float4*       op = o4 + q4;

  // ---------------- phase 1: zero-carry partial scan (backward) ----------------
  float4 vn = vp[(t_hi + 1) * B4];
  float4 p  = make_float4(0.f, 0.f, 0.f, 0.f);

  int t = t_hi;
  if (is_top) {
    // len 31: peel 3 rows (one batched round trip) -> 28 left (7 batches).
    float4 rr[3], vv[3];
#pragma unroll
    for (int k = 0; k < 3; ++k) { rr[k] = rp[(t - k) * B4]; vv[k] = vp[(t - k) * B4]; }
#pragma unroll
    for (int k = 0; k < 3; ++k) {
      STEP4(rr[k], vv[k])
      op[(t - k) * B4] = p;
      vn = vv[k];
    }
    t -= 3;
  }

  {
    float4 rA[4], vA[4], rB[4], vB[4];
    int tcur = t;          // top t of next batch to compute
    int tp   = t - 4;      // top t of next batch to prefetch

    P1_LOADQ(rA, vA, tcur)
    const int nb = ((t - t_lo + 1) >> 2) - 1;     // 7 (len 32) or 6 (len 28)
    int i = 0;
    for (; i + 2 <= nb; i += 2) {
      P1_BODY(rB, vB, rA, vA)
      P1_BODY(rA, vA, rB, vB)
    }
    if (i < nb) {
      P1_BODY(rB, vB, rA, vA)
      P1_EPI(rB, vB)
    } else {
      P1_EPI(rA, vA)
    }
  }
  // p == this chunk's aggregate A (zero-carry partial at t_lo).

  // ---------------- phase 2: combine (LDS local + partner handshake) ----------
  aggs[wl][lane] = p;
  __syncthreads();

  float4 K;
  if (upper) {
    K = make_float4(0.f, 0.f, 0.f, 0.f);
  } else {
    // wait for partner (upper half of same strip) to publish C_15
    while (__hip_atomic_load(&flag_ws[s * 16], __ATOMIC_ACQUIRE,
                             __HIP_MEMORY_SCOPE_AGENT) == 0u)
      __builtin_amdgcn_s_sleep(2);
    float* src = agg_ws + s * 256 + lane * 4;
    K.x = __hip_atomic_load(src + 0, __ATOMIC_RELAXED, __HIP_MEMORY_SCOPE_AGENT);
    K.y = __hip_atomic_load(src + 1, __ATOMIC_RELAXED, __HIP_MEMORY_SCOPE_AGENT);
    K.z = __hip_atomic_load(src + 2, __ATOMIC_RELAXED, __HIP_MEMORY_SCOPE_AGENT);
    K.w = __hip_atomic_load(src + 3, __ATOMIC_RELAXED, __HIP_MEMORY_SCOPE_AGENT);
  }
  // K = carry into local chunk 15's top; fold local later chunks down to wl+1.
  for (int j = NW - 1; j > wl; --j) {             // wave-uniform trip count
    float4 a = aggs[j][lane];
    K.x = a.x + gS32 * K.x;
    K.y = a.y + gS32 * K.y;
    K.z = a.z + gS32 * K.z;
    K.w = a.w + gS32 * K.w;
  }
  // K == C_chunk (true carry into own chunk). For global chunk 31, K == 0.

  if (upper && wl == 0) {
    // publish C_15 = A_16 + g^32 * C_16  (p = A_16, K = C_16 here)
    float* dst = agg_ws + s * 256 + lane * 4;
    __hip_atomic_store(dst + 0, p.x + gS32 * K.x, __ATOMIC_RELAXED, __HIP_MEMORY_SCOPE_AGENT);
    __hip_atomic_store(dst + 1, p.y + gS32 * K.y, __ATOMIC_RELAXED, __HIP_MEMORY_SCOPE_AGENT);
    __hip_atomic_store(dst + 2, p.z + gS32 * K.z, __ATOMIC_RELAXED, __HIP_MEMORY_SCOPE_AGENT);
    __hip_atomic_store(dst + 3, p.w + gS32 * K.w, __ATOMIC_RELAXED, __HIP_MEMORY_SCOPE_AGENT);
    __threadfence();
    if (lane == 0)
      __hip_atomic_store(&flag_ws[s * 16], 1u, __ATOMIC_RELEASE, __HIP_MEMORY_SCOPE_AGENT);
  }

  // ---------------- phase 3: fix-up own chunk (forward, cache-hot) ------------
  if (!is_top) {
    // x(t) = g^(t_hi+1-t) * K; at t_lo that is g^32 * K, then *= 1/g going up.
    float4 x = make_float4(gS32 * K.x, gS32 * K.y, gS32 * K.z, gS32 * K.w);
    float4 oA[4], oB[4];
    int uc  = t_lo;        // next batch to compute (forward)
    int up2 = t_lo + 4;    // next batch to prefetch

    P3_LOADQ(oA, uc)
    // 8 batches -> 7 bodies: alternate (B,A)/(A,B), epilogue on B.
    P3_BODY(oB, oA)
    P3_BODY(oA, oB)
    P3_BODY(oB, oA)
    P3_BODY(oA, oB)
    P3_BODY(oB, oA)
    P3_BODY(oA, oB)
    P3_BODY(oB, oA)
    P3_EPI(oB)
  }
}

extern "C" void kernel_launch(void* const* d_in, const int* in_sizes, int n_in,
                              void* d_out, int out_size, void* d_ws, size_t ws_size,
                              hipStream_t stream) {
  const float4* r4 = (const float4*)d_in[0];
  const float4* v4 = (const float4*)d_in[1];
  float4* o4 = (float4*)d_out;

  // workspace: 128 strips x 256 floats aggregates (128 KB), then 128 flags
  // at 64 B stride (8 KB).
  float*    agg_ws  = (float*)d_ws;
  unsigned* flag_ws = (unsigned*)((char*)d_ws + 128 * 1024);
  float gS32 = (float)pow((double)GL_F, 32);

  // reset flags every launch (stream-ordered, graph-capturable)
  hipMemsetAsync((void*)flag_ws, 0, 128 * 64, stream);

  // NORMAL launch (the A/B vs R4): 256 blocks x 1024 threads. Producers
  // (blocks 0..127) precede consumers (128..255) in FIFO dispatch order.
  gae_fused<<<dim3(256), dim3(1024), 0, stream>>>(r4, v4, o4, agg_ws, flag_ws, gS32);
}

// Round 6
// 329.705 us; speedup vs baseline: 1.4308x; 1.1676x over previous
//
#include <hip/hip_runtime.h>
#include <math.h>

// GAE backward scan, single fused kernel. R2-proven geometry + half-register
// partials (traffic reduction).
//   adv[t] = delta[t] + g*adv[t+1], delta[t] = r[t] + 0.99*v[t+1] - v[t], g=0.9405
//
// History: R0-R2 latency knobs -> 3.0 TB/s plateau; R3-R5 restructures (coop,
// f4, half-split, bursts 512B->1KB) all regressed => access-pattern efficiency
// is ~3 TB/s regardless; remaining lever is TRAFFIC.
// R6: block = 64 f2 columns x 16 waves = 16 t-chunks of 64 rows (exact R2
// layout, plain launch, no workspace). Each wave keeps the TOP 32 rows of its
// chunk [t_hi-31, t_hi] in registers (psv[32], fully unrolled => static
// indices, no scratch): no partial store, no re-read -- phase 3 writes them
// once (NT). Bottom 32 rows keep the R2 store/RMW path (depth-1 quad pipeline
// to fit VGPR cap 128 at 1024 thr).
// Issued traffic 620 -> 496 MB; HBM ~456 -> ~375 MB.

#define T_OUT 1023
#define B2    16384          // 32768 floats / 2 per lane
#define NW    16             // waves (= chunks) per block
#define S_CH  64             // chunk length (last chunk: 63)

#define GAMMA_F 0.99f
#define GL_F    0.9405f      // (float)(0.99*0.95)
#define INVG_F  1.0632642212653909f   // 1/0.9405

typedef float f2v __attribute__((ext_vector_type(2)));

static __device__ __forceinline__ void nt_store_f2(float2* dst, float2 v) {
  __builtin_nontemporal_store(*(const f2v*)&v, (f2v*)dst);
}

#define STEP2(r, v)                                  \
  p.x = (r).x + GAMMA_F * vn.x - (v).x + GL_F * p.x; \
  p.y = (r).y + GAMMA_F * vn.y - (v).y + GL_F * p.y;

// ---- phase-1 bottom-half pipeline (backward in t, single-quad bodies) ----
#define P1_LOADQ(rB_, vB_, tt)                       \
  _Pragma("unroll")                                  \
  for (int k = 0; k < 4; ++k) {                      \
    rB_[k] = rp[((tt) - k) * B2];                    \
    vB_[k] = vp[((tt) - k) * B2];                    \
  }

#define P1_COMPQ(rB_, vB_, tt)                       \
  _Pragma("unroll")                                  \
  for (int k = 0; k < 4; ++k) {                      \
    STEP2(rB_[k], vB_[k])                            \
    op[((tt) - k) * B2] = p;                         \
    vn = vB_[k];                                     \
  }

#define P1_BODY(rP, vP, rX, vX)                      \
  P1_LOADQ(rP, vP, tp)                               \
  __builtin_amdgcn_sched_barrier(0);                 \
  P1_COMPQ(rX, vX, tcur)                             \
  tcur -= 4; tp -= 4;

#define P1_EPI(rX, vX) P1_COMPQ(rX, vX, tcur)

// ---- phase-3 bottom-half pipeline (forward in t, += x, x *= 1/g per row) ----
#define P3_LOADQ(oB_, uu)                            \
  _Pragma("unroll")                                  \
  for (int k = 0; k < 4; ++k) oB_[k] = op[((uu) + k) * B2];

#define P3_COMPQ(oB_, uu)                            \
  _Pragma("unroll")                                  \
  for (int k = 0; k < 4; ++k) {                      \
    oB_[k].x += x.x; oB_[k].y += x.y;                \
    nt_store_f2(&op[((uu) + k) * B2], oB_[k]);       \
    x.x *= INVG_F; x.y *= INVG_F;                    \
  }

#define P3_BODY(oP, oX)                              \
  P3_LOADQ(oP, up2)                                  \
  __builtin_amdgcn_sched_barrier(0);                 \
  P3_COMPQ(oX, uc)                                   \
  uc += 4; up2 += 4;

#define P3_EPI(oX) P3_COMPQ(oX, uc)

__global__ __launch_bounds__(1024, 4) void gae_fused(
    const float2* __restrict__ r2, const float2* __restrict__ v2,
    float2* __restrict__ o2, float gS_full, float gS_last) {
  __shared__ float2 aggs[NW][64];

  const int lane = threadIdx.x & 63;
  const int w    = threadIdx.x >> 6;              // wave id == chunk id (uniform)
  const int q    = blockIdx.x * 64 + lane;        // float2 column index

  const int t_lo = w * S_CH;
  const int t_hi = (w == NW - 1) ? (T_OUT - 1) : (t_lo + S_CH - 1);

  const float2* rp = r2 + q;
  const float2* vp = v2 + q;
  float2*       op = o2 + q;

  // -------- phase 1a: top 32 rows [t_hi-31, t_hi], partials -> REGISTERS -----
  // psv[j] = zero-carry partial at row (t_hi - j), j = 0..31. Fully unrolled
  // (static indices -> stays in VGPRs, rule #20). No global stores here.
  float2 vn = vp[(t_hi + 1) * B2];
  float2 p  = make_float2(0.f, 0.f);
  float2 psv[32];

#pragma unroll
  for (int j = 0; j < 8; ++j) {
    float2 rq[4], vq[4];
#pragma unroll
    for (int k = 0; k < 4; ++k) {
      rq[k] = rp[(t_hi - (j * 4 + k)) * B2];
      vq[k] = vp[(t_hi - (j * 4 + k)) * B2];
    }
#pragma unroll
    for (int k = 0; k < 4; ++k) {
      STEP2(rq[k], vq[k])
      psv[j * 4 + k] = p;
      vn = vq[k];
    }
  }

  // -------- phase 1b: bottom rows [t_lo, t_hi-32], partials -> global --------
  // len = 32 (chunks 0..14) or 31 (chunk 15).
  int t = t_hi - 32;
  const int pre = (t - t_lo + 1) & 3;             // 0 or 3 (chunk 15)
  for (int k = 0; k < pre; ++k, --t) {
    float2 r = rp[t * B2];
    float2 v = vp[t * B2];
    STEP2(r, v)
    op[t * B2] = p;
    vn = v;
  }
  {
    float2 rA[4], vA[4], rB[4], vB[4];
    int tcur = t;          // top t of next quad to compute
    int tp   = t - 4;      // top t of next quad to prefetch

    P1_LOADQ(rA, vA, tcur)
    const int nb = ((t - t_lo + 1) >> 2) - 1;     // 7 (len 32) or 6 (len 28)
    int i = 0;
    for (; i + 2 <= nb; i += 2) {
      P1_BODY(rB, vB, rA, vA)
      P1_BODY(rA, vA, rB, vB)
    }
    if (i < nb) {
      P1_BODY(rB, vB, rA, vA)
      P1_EPI(rB, vB)
    } else {
      P1_EPI(rA, vA)
    }
  }
  // p == this chunk's full zero-carry aggregate (both segments accumulated).

  // ---------------- phase 2: combine chunk aggregates via LDS ----------------
  aggs[w][lane] = p;
  __syncthreads();

  float2 K = make_float2(0.f, 0.f);
  for (int j = NW - 1; j > w; --j) {              // wave-uniform trip count
    const float gj = (j == NW - 1) ? gS_last : gS_full;
    float2 a = aggs[j][lane];
    K.x = a.x + gj * K.x;
    K.y = a.y + gj * K.y;
  }
  // K == true carry into own chunk (0 for chunk 15).

  // -------- phase 3a: bottom-half RMW fix-up (L2-hot partials), fwd in t -----
  if (w < NW - 1) {                               // chunk 15: K == 0, skip RMW
    // x(t) = g^(t_hi+1-t) * K; at t_lo that is g^64 * K, *= 1/g ascending.
    // Bottom half ends at t_hi-32 = t_lo+31 with factor g^33. (len 32 here.)
    float2 x = make_float2(gS_full * K.x, gS_full * K.y);
    float2 oA[4], oB[4];
    int uc  = t_lo;        // next quad to compute (forward)
    int up2 = t_lo + 4;    // next quad to prefetch

    P3_LOADQ(oA, uc)
    // 8 quads -> 7 bodies alternating, epilogue on B.
    P3_BODY(oB, oA)
    P3_BODY(oA, oB)
    P3_BODY(oB, oA)
    P3_BODY(oA, oB)
    P3_BODY(oB, oA)
    P3_BODY(oA, oB)
    P3_BODY(oB, oA)
    P3_EPI(oB)
  }

  // -------- phase 3b: top-half single write from registers (NT, no read) -----
  // out[t_hi - j] = psv[j] + g^(j+1) * K. For chunk 15, K == 0 -> pure store.
  {
    float2 x = make_float2(GL_F * K.x, GL_F * K.y);   // g^1 * K at j = 0
#pragma unroll
    for (int j = 0; j < 32; ++j) {
      float2 o;
      o.x = psv[j].x + x.x;
      o.y = psv[j].y + x.y;
      nt_store_f2(&op[(t_hi - j) * B2], o);
      x.x *= GL_F;
      x.y *= GL_F;
    }
  }
}

extern "C" void kernel_launch(void* const* d_in, const int* in_sizes, int n_in,
                              void* d_out, int out_size, void* d_ws, size_t ws_size,
                              hipStream_t stream) {
  const float2* r2 = (const float2*)d_in[0];
  const float2* v2 = (const float2*)d_in[1];
  float2* o2 = (float2*)d_out;

  const double g = (double)GL_F;
  const float gS_full = (float)pow(g, S_CH);       // g^64, chunks 0..14
  const float gS_last = (float)pow(g, S_CH - 1);   // g^63, chunk 15 (63 rows)

  // 16384 float2 cols / 64 lanes = 256 blocks -> 1 block (16 waves) per CU.
  gae_fused<<<dim3(B2 / 64), dim3(1024), 0, stream>>>(r2, v2, o2, gS_full, gS_last);
}